// Round 1
// 528.338 us; speedup vs baseline: 1.2152x; 1.2152x over previous
//
#include <hip/hip_runtime.h>

// Bilinear flow warp: input1 [B,C,H,W] fp32, input2 [B,2,H,W] flow (dx,dy).
// out[b,c,i,j] = bilinear sample of input1[b,c] at (i+fy, j+fx), OOB -> 0.
//
// v2 strategy: the per-pixel flow is random (sigma=4px), so in the [B,C,H,W]
// layout every gather lane hits its own cache line: 4 corners x 64 channels
// = 256 scattered-dword instructions/wave ~= 16K cache-line transactions/wave
// -> TA-transaction-bound at ~377us (measured; 1 line/cyc/CU model matches).
// Fix: stage image channels-last [B,H,W,C] in the workspace. Each pixel's
// 64-channel vector is 256B contiguous & aligned, so one (pixel,corner)
// gather = ONE coalesced 4-line load (lane=channel). 16x fewer transactions;
// the extra transpose pass is pure streaming BW.
constexpr int B = 8, C = 64, H = 256, W = 448;
constexpr int HW = H * W;          // 114688
constexpr int NPIX = B * HW;       // 917504
constexpr int BLK = 256;
constexpr int XCDS = 8;

// ---- fallback (v1) config ----
constexpr int NBLOCKS_V1 = NPIX / BLK;              // 3584
constexpr int BLOCKS_PER_XCD_V1 = NBLOCKS_V1 / XCDS;

// ---- v2 config ----
constexpr int TILE = 64;                            // pixels per block / channels
constexpr int TILES_PER_ROW = W / TILE;             // 7
constexpr int TILES_PER_IMG = HW / TILE;            // 1792
constexpr int NBLOCKS_V2 = B * TILES_PER_IMG;       // 14336
constexpr int BLOCKS_PER_XCD_V2 = NBLOCKS_V2 / XCDS;// 1792 == one image per XCD
constexpr size_t WS_NEEDED = (size_t)B * HW * C * sizeof(float); // 224 MB

// ---------------------------------------------------------------------------
// Kernel A: [B,C,HW] -> [B,HW,C] transpose, 64x64 LDS tile, +1 pad.
// ---------------------------------------------------------------------------
__global__ __launch_bounds__(256) void transpose_kernel(
    const float* __restrict__ img,   // [B,C,HW]
    float* __restrict__ tmp)         // [B,HW,C]
{
    __shared__ float lds[64][65];

    int blk = blockIdx.x;
    int b   = blk / TILES_PER_IMG;
    int t   = blk - b * TILES_PER_IMG;
    int hw0 = t * TILE;

    int tx = threadIdx.x & 63;   // hw on load, channel on store
    int ty = threadIdx.x >> 6;   // 0..3

    // load: lanes = consecutive hw (coalesced 256B per row)
    const float* src = img + (size_t)b * C * HW + hw0 + tx;
    #pragma unroll
    for (int k = 0; k < 16; ++k) {
        int c = ty + 4 * k;
        lds[c][tx] = src[(size_t)c * HW];
    }
    __syncthreads();

    // store: lanes = consecutive channel (coalesced 256B per pixel)
    float* dst = tmp + ((size_t)b * HW + hw0) * C + tx;
    #pragma unroll
    for (int k = 0; k < 16; ++k) {
        int px = ty + 4 * k;
        dst[(size_t)px * C] = lds[tx][px];
    }
}

// ---------------------------------------------------------------------------
// Kernel B: gather from channels-last tmp. One block = 64 consecutive pixels
// of one row; each wave owns 16 pixels, lane = channel. Corner addresses are
// wave-uniform; each gather is a fully-coalesced 256B load. Results staged in
// LDS [px][c] (+1 pad), then written out channel-major, coalesced.
// ---------------------------------------------------------------------------
__global__ __launch_bounds__(256) void gather_kernel(
    const float* __restrict__ tmp,   // [B,HW,C]
    const float* __restrict__ flow,  // [B,2,H,W]
    float* __restrict__ out)         // [B,C,H,W]
{
    __shared__ float sm[64][65];

    // XCD swizzle: image b -> XCD b; rows ascend within an XCD so the
    // +/-12-row gather band (~3.1MB channels-last) stays in one 4MB L2.
    int bid = blockIdx.x;
    int swz = (bid % XCDS) * BLOCKS_PER_XCD_V2 + (bid / XCDS);

    int b  = swz / TILES_PER_IMG;
    int t  = swz - b * TILES_PER_IMG;
    int i  = t / TILES_PER_ROW;
    int j0 = (t - i * TILES_PER_ROW) * TILE;

    int lane = threadIdx.x & 63;   // channel during gather
    int wv   = threadIdx.x >> 6;   // 0..3, wave id

    const float* fb = flow + (size_t)b * 2 * HW;
    const size_t img_base = (size_t)b * H * (size_t)W;

    #pragma unroll 4
    for (int pp = 0; pp < 16; ++pp) {
        int p  = wv * 16 + pp;     // pixel slot 0..63 (wave-uniform)
        int j  = j0 + p;
        int ij = i * W + j;

        // wave-uniform broadcast loads (same addr for all lanes)
        float fx = fb[ij];
        float fy = fb[HW + ij];

        float x = (float)j + fx;
        float y = (float)i + fy;

        float x0f = floorf(x), y0f = floorf(y);
        int   x0  = (int)x0f,  y0  = (int)y0f;
        float wx1 = x - x0f,   wy1 = y - y0f;
        float wx0 = 1.0f - wx1, wy0 = 1.0f - wy1;

        // per-corner validity (matches reference: valid iff 0<=coord<=dim-1)
        bool vx0 = (x0 >= 0)  & (x0 <= W - 1);
        bool vx1 = (x0 >= -1) & (x0 <= W - 2);
        bool vy0 = (y0 >= 0)  & (y0 <= H - 1);
        bool vy1 = (y0 >= -1) & (y0 <= H - 2);

        float w00 = (vy0 & vx0) ? wy0 * wx0 : 0.0f;
        float w01 = (vy0 & vx1) ? wy0 * wx1 : 0.0f;
        float w10 = (vy1 & vx0) ? wy1 * wx0 : 0.0f;
        float w11 = (vy1 & vx1) ? wy1 * wx1 : 0.0f;

        int xi0 = min(max(x0, 0),     W - 1);
        int xi1 = min(max(x0 + 1, 0), W - 1);
        int yi0 = min(max(y0, 0),     H - 1);
        int yi1 = min(max(y0 + 1, 0), H - 1);

        // coalesced 256B gathers: wave-uniform pixel base + lane(=channel)
        const float* r0 = tmp + (img_base + (size_t)yi0 * W) * C + lane;
        const float* r1 = tmp + (img_base + (size_t)yi1 * W) * C + lane;
        float v00 = r0[(size_t)xi0 * C];
        float v01 = r0[(size_t)xi1 * C];
        float v10 = r1[(size_t)xi0 * C];
        float v11 = r1[(size_t)xi1 * C];

        sm[p][lane] = w00 * v00 + w01 * v01 + w10 * v10 + w11 * v11;
    }
    __syncthreads();

    // write-out: lanes = consecutive px within the row segment (coalesced)
    int px = threadIdx.x & 63;
    int cg = threadIdx.x >> 6;
    float* ob = out + (size_t)b * C * HW + (size_t)i * W + j0 + px;
    #pragma unroll
    for (int k = 0; k < 16; ++k) {
        int c = cg + 4 * k;
        ob[(size_t)c * HW] = sm[px][c];
    }
}

// ---------------------------------------------------------------------------
// Fallback (v1, proven 377us/dispatch): used only if workspace is too small.
// ---------------------------------------------------------------------------
__global__ __launch_bounds__(256) void warp_kernel(
    const float* __restrict__ img,
    const float* __restrict__ flow,
    float* __restrict__ out)
{
    int bid = blockIdx.x;
    int swz = (bid % XCDS) * BLOCKS_PER_XCD_V1 + (bid / XCDS);
    int pix = swz * BLK + threadIdx.x;

    int b  = pix / HW;
    int ij = pix - b * HW;
    int i  = ij / W;
    int j  = ij - i * W;

    float fx = flow[(size_t)(b * 2 + 0) * HW + ij];
    float fy = flow[(size_t)(b * 2 + 1) * HW + ij];

    float x = (float)j + fx;
    float y = (float)i + fy;

    float x0f = floorf(x), y0f = floorf(y);
    int   x0  = (int)x0f,  y0  = (int)y0f;
    float wx1 = x - x0f,   wy1 = y - y0f;
    float wx0 = 1.0f - wx1, wy0 = 1.0f - wy1;

    bool vx0 = (x0 >= 0)  & (x0 <= W - 1);
    bool vx1 = (x0 >= -1) & (x0 <= W - 2);
    bool vy0 = (y0 >= 0)  & (y0 <= H - 1);
    bool vy1 = (y0 >= -1) & (y0 <= H - 2);

    float w00 = (vy0 & vx0) ? wy0 * wx0 : 0.0f;
    float w01 = (vy0 & vx1) ? wy0 * wx1 : 0.0f;
    float w10 = (vy1 & vx0) ? wy1 * wx0 : 0.0f;
    float w11 = (vy1 & vx1) ? wy1 * wx1 : 0.0f;

    int xi0 = min(max(x0, 0),     W - 1);
    int xi1 = min(max(x0 + 1, 0), W - 1);
    int yi0 = min(max(y0, 0),     H - 1);
    int yi1 = min(max(y0 + 1, 0), H - 1);

    int o00 = yi0 * W + xi0;
    int o01 = yi0 * W + xi1;
    int o10 = yi1 * W + xi0;
    int o11 = yi1 * W + xi1;

    const float* ib = img + (size_t)b * C * HW;
    float*       ob = out + (size_t)b * C * HW + ij;

    #pragma unroll
    for (int cb = 0; cb < C; cb += 8) {
        float v00[8], v01[8], v10[8], v11[8];
        #pragma unroll
        for (int u = 0; u < 8; ++u) {
            const float* q = ib + (size_t)(cb + u) * HW;
            v00[u] = q[o00];
            v01[u] = q[o01];
            v10[u] = q[o10];
            v11[u] = q[o11];
        }
        #pragma unroll
        for (int u = 0; u < 8; ++u) {
            ob[(size_t)(cb + u) * HW] =
                w00 * v00[u] + w01 * v01[u] + w10 * v10[u] + w11 * v11[u];
        }
    }
}

extern "C" void kernel_launch(void* const* d_in, const int* in_sizes, int n_in,
                              void* d_out, int out_size, void* d_ws, size_t ws_size,
                              hipStream_t stream) {
    const float* img  = (const float*)d_in[0];
    const float* flow = (const float*)d_in[1];
    float* out = (float*)d_out;

    if (ws_size >= WS_NEEDED && d_ws != nullptr) {
        float* tmp = (float*)d_ws;
        transpose_kernel<<<dim3(NBLOCKS_V2), dim3(BLK), 0, stream>>>(img, tmp);
        gather_kernel<<<dim3(NBLOCKS_V2), dim3(BLK), 0, stream>>>(tmp, flow, out);
    } else {
        warp_kernel<<<dim3(NBLOCKS_V1), dim3(BLK), 0, stream>>>(img, flow, out);
    }
}

// Round 2
// 509.894 us; speedup vs baseline: 1.2591x; 1.0362x over previous
//
#include <hip/hip_runtime.h>

// Bilinear flow warp: input1 [B,C,H,W] fp32, input2 [B,2,H,W] flow (dx,dy).
// out[b,c,i,j] = bilinear sample of input1[b,c] at (i+fy, j+fx), OOB -> 0.
//
// v3: two-pass channels-last (v2) + VALU de-duplication.
// v2 measurement: gather = 150us, VALUBusy 65%, HBM 30% -> VALU-issue-bound.
// Cause: per-pixel scalar math (flow load, floor, clamps, weights, 64-bit
// addressing) replicated across all 64 lanes, ~40 VALU/pixel.
// v3: lane-parallel metadata precompute (16 pixels at once per wave, no
// barrier needed -- register-only, wave-local), then readlane -> SGPR
// broadcast so each gather is global_load_dword v, v_lane, s[base] with
// SALU-only addressing. Write-out and transpose vectorized to dwordx4.
constexpr int B = 8, C = 64, H = 256, W = 448;
constexpr int HW = H * W;          // 114688
constexpr int NPIX = B * HW;       // 917504
constexpr int BLK = 256;
constexpr int XCDS = 8;

// ---- fallback (v1) config ----
constexpr int NBLOCKS_V1 = NPIX / BLK;              // 3584
constexpr int BLOCKS_PER_XCD_V1 = NBLOCKS_V1 / XCDS;

// ---- v2/v3 config ----
constexpr int TILE = 64;                            // pixels per block / channels
constexpr int TILES_PER_ROW = W / TILE;             // 7
constexpr int TILES_PER_IMG = HW / TILE;            // 1792
constexpr int NBLOCKS_V2 = B * TILES_PER_IMG;       // 14336
constexpr int BLOCKS_PER_XCD_V2 = NBLOCKS_V2 / XCDS;// 1792 == one image per XCD
constexpr size_t WS_NEEDED = (size_t)B * HW * C * sizeof(float); // 224 MB

// ---------------------------------------------------------------------------
// Kernel A: [B,C,HW] -> [B,HW,C] transpose, 64x64 tile, dwordx4 global both
// sides. LDS [64][65]: all scalar LDS access patterns are <=2-way (free).
// ---------------------------------------------------------------------------
__global__ __launch_bounds__(256) void transpose_kernel(
    const float* __restrict__ img,   // [B,C,HW]
    float* __restrict__ tmp)         // [B,HW,C]
{
    __shared__ float lds[64][65];

    int blk = blockIdx.x;
    int b   = blk / TILES_PER_IMG;
    int t   = blk - b * TILES_PER_IMG;
    int hw0 = t * TILE;

    // load: lane covers 4 consecutive px of one channel row (coalesced 256B)
    int pc = threadIdx.x & 15;       // px chunk
    int cg = threadIdx.x >> 4;       // 0..15
    const float* src = img + (size_t)b * C * HW + hw0 + 4 * pc;
    #pragma unroll
    for (int k = 0; k < 4; ++k) {
        int c = cg + 16 * k;
        float4 v = *(const float4*)(src + (size_t)c * HW);
        // banks: (c + 4pc + u) mod 32 over a wave -> 2-way, free
        lds[c][4 * pc + 0] = v.x;
        lds[c][4 * pc + 1] = v.y;
        lds[c][4 * pc + 2] = v.z;
        lds[c][4 * pc + 3] = v.w;
    }
    __syncthreads();

    // store: lane covers 4 consecutive channels of one pixel (coalesced 256B)
    int lc = threadIdx.x & 15;       // channel chunk
    int pg = threadIdx.x >> 4;       // 0..15
    float* dst = tmp + ((size_t)b * HW + hw0) * C + 4 * lc;
    #pragma unroll
    for (int k = 0; k < 4; ++k) {
        int px = pg + 16 * k;
        float4 v;
        // banks: (4lc + u + px) mod 32 over a wave -> 2-way, free
        v.x = lds[4 * lc + 0][px];
        v.y = lds[4 * lc + 1][px];
        v.z = lds[4 * lc + 2][px];
        v.w = lds[4 * lc + 3][px];
        *(float4*)(dst + (size_t)px * C) = v;
    }
}

// ---------------------------------------------------------------------------
// Kernel B: gather from channels-last tmp. One block = 64 consecutive px of
// one row; each wave owns 16 px, lane = channel during gather.
// Phase 1: lanes compute 16 pixels' metadata in parallel (byte offsets +
// weights) -- register-only, no barrier. Main loop: readlane -> SGPR, loads
// are SGPR-base + lane*4 (zero VALU addressing), v_fmac with SGPR weights.
// ---------------------------------------------------------------------------
__global__ __launch_bounds__(256) void gather_kernel(
    const float* __restrict__ tmp,   // [B,HW,C]
    const float* __restrict__ flow,  // [B,2,H,W]
    float* __restrict__ out)         // [B,C,H,W]
{
    __shared__ float sm[64][65];     // [channel][pixel], pad -> all phases free

    // XCD swizzle: image b -> XCD b (gather band stays in one 4MB L2)
    int bid = blockIdx.x;
    int swz = (bid % XCDS) * BLOCKS_PER_XCD_V2 + (bid / XCDS);

    int b  = swz / TILES_PER_IMG;
    int t  = swz - b * TILES_PER_IMG;
    int i  = t / TILES_PER_ROW;
    int j0 = (t - i * TILES_PER_ROW) * TILE;

    int lane = threadIdx.x & 63;
    int wv   = threadIdx.x >> 6;     // 0..3

    // ---- phase 1: metadata for pixel p = wv*16 + (lane&15), lane-parallel
    // (replicated x4 across lane>>4 -- harmless, keeps exec full/uniform)
    int pl = lane & 15;
    int p1 = wv * 16 + pl;
    int j  = j0 + p1;
    int ij = i * W + j;

    const float* fb = flow + (size_t)b * 2 * HW;
    float fx = fb[ij];               // 16 consecutive addrs, coalesced
    float fy = fb[HW + ij];

    float x = (float)j + fx;
    float y = (float)i + fy;

    float x0f = floorf(x), y0f = floorf(y);
    int   x0  = (int)x0f,  y0  = (int)y0f;
    float wx1 = x - x0f,   wy1 = y - y0f;
    float wx0 = 1.0f - wx1, wy0 = 1.0f - wy1;

    // per-corner validity (matches reference: valid iff 0<=coord<=dim-1)
    bool vx0 = (x0 >= 0)  & (x0 <= W - 1);
    bool vx1 = (x0 >= -1) & (x0 <= W - 2);
    bool vy0 = (y0 >= 0)  & (y0 <= H - 1);
    bool vy1 = (y0 >= -1) & (y0 <= H - 2);

    float w00r = (vy0 & vx0) ? wy0 * wx0 : 0.0f;
    float w01r = (vy0 & vx1) ? wy0 * wx1 : 0.0f;
    float w10r = (vy1 & vx0) ? wy1 * wx0 : 0.0f;
    float w11r = (vy1 & vx1) ? wy1 * wx1 : 0.0f;

    int xi0 = min(max(x0, 0),     W - 1);
    int xi1 = min(max(x0 + 1, 0), W - 1);
    int yi0 = min(max(y0, 0),     H - 1);
    int yi1 = min(max(y0 + 1, 0), H - 1);

    // byte offsets into this image's channels-last block: (y*W+x)*C*4
    int o00r = (yi0 * W + xi0) << 8;
    int o01r = (yi0 * W + xi1) << 8;
    int o10r = (yi1 * W + xi0) << 8;
    int o11r = (yi1 * W + xi1) << 8;

    const char* tb = (const char*)(tmp + (size_t)b * HW * C);

    // ---- main loop: 16 pixels per wave, lane = channel
    #pragma unroll 4
    for (int pp = 0; pp < 16; ++pp) {
        int   o00 = __builtin_amdgcn_readlane(o00r, pp);
        int   o01 = __builtin_amdgcn_readlane(o01r, pp);
        int   o10 = __builtin_amdgcn_readlane(o10r, pp);
        int   o11 = __builtin_amdgcn_readlane(o11r, pp);
        float w00 = __int_as_float(__builtin_amdgcn_readlane(__float_as_int(w00r), pp));
        float w01 = __int_as_float(__builtin_amdgcn_readlane(__float_as_int(w01r), pp));
        float w10 = __int_as_float(__builtin_amdgcn_readlane(__float_as_int(w10r), pp));
        float w11 = __int_as_float(__builtin_amdgcn_readlane(__float_as_int(w11r), pp));

        const float* q00 = (const float*)(tb + (unsigned)o00);
        const float* q01 = (const float*)(tb + (unsigned)o01);
        const float* q10 = (const float*)(tb + (unsigned)o10);
        const float* q11 = (const float*)(tb + (unsigned)o11);

        float v00 = q00[lane];       // coalesced 256B, SGPR base + lane*4
        float v01 = q01[lane];
        float v10 = q10[lane];
        float v11 = q11[lane];

        float acc = w00 * v00 + w01 * v01 + w10 * v10 + w11 * v11;
        sm[lane][wv * 16 + pp] = acc;   // banks: lane + const -> 2-way, free
    }
    __syncthreads();

    // ---- write-out: float4 along px, coalesced 256B per channel row
    int pg = threadIdx.x & 15;       // px chunk
    int cg = threadIdx.x >> 4;       // 0..15
    float* ob = out + (size_t)b * C * HW + (size_t)i * W + j0 + 4 * pg;
    #pragma unroll
    for (int k = 0; k < 4; ++k) {
        int c = cg + 16 * k;
        float4 v;
        // banks: (c + 4pg + u) mod 32 over a wave -> 2-way, free
        v.x = sm[c][4 * pg + 0];
        v.y = sm[c][4 * pg + 1];
        v.z = sm[c][4 * pg + 2];
        v.w = sm[c][4 * pg + 3];
        *(float4*)(ob + (size_t)c * HW) = v;
    }
}

// ---------------------------------------------------------------------------
// Fallback (v1, proven 377us/dispatch): used only if workspace is too small.
// ---------------------------------------------------------------------------
__global__ __launch_bounds__(256) void warp_kernel(
    const float* __restrict__ img,
    const float* __restrict__ flow,
    float* __restrict__ out)
{
    int bid = blockIdx.x;
    int swz = (bid % XCDS) * BLOCKS_PER_XCD_V1 + (bid / XCDS);
    int pix = swz * BLK + threadIdx.x;

    int b  = pix / HW;
    int ij = pix - b * HW;
    int i  = ij / W;
    int j  = ij - i * W;

    float fx = flow[(size_t)(b * 2 + 0) * HW + ij];
    float fy = flow[(size_t)(b * 2 + 1) * HW + ij];

    float x = (float)j + fx;
    float y = (float)i + fy;

    float x0f = floorf(x), y0f = floorf(y);
    int   x0  = (int)x0f,  y0  = (int)y0f;
    float wx1 = x - x0f,   wy1 = y - y0f;
    float wx0 = 1.0f - wx1, wy0 = 1.0f - wy1;

    bool vx0 = (x0 >= 0)  & (x0 <= W - 1);
    bool vx1 = (x0 >= -1) & (x0 <= W - 2);
    bool vy0 = (y0 >= 0)  & (y0 <= H - 1);
    bool vy1 = (y0 >= -1) & (y0 <= H - 2);

    float w00 = (vy0 & vx0) ? wy0 * wx0 : 0.0f;
    float w01 = (vy0 & vx1) ? wy0 * wx1 : 0.0f;
    float w10 = (vy1 & vx0) ? wy1 * wx0 : 0.0f;
    float w11 = (vy1 & vx1) ? wy1 * wx1 : 0.0f;

    int xi0 = min(max(x0, 0),     W - 1);
    int xi1 = min(max(x0 + 1, 0), W - 1);
    int yi0 = min(max(y0, 0),     H - 1);
    int yi1 = min(max(y0 + 1, 0), H - 1);

    int o00 = yi0 * W + xi0;
    int o01 = yi0 * W + xi1;
    int o10 = yi1 * W + xi0;
    int o11 = yi1 * W + xi1;

    const float* ib = img + (size_t)b * C * HW;
    float*       ob = out + (size_t)b * C * HW + ij;

    #pragma unroll
    for (int cb = 0; cb < C; cb += 8) {
        float v00[8], v01[8], v10[8], v11[8];
        #pragma unroll
        for (int u = 0; u < 8; ++u) {
            const float* q = ib + (size_t)(cb + u) * HW;
            v00[u] = q[o00];
            v01[u] = q[o01];
            v10[u] = q[o10];
            v11[u] = q[o11];
        }
        #pragma unroll
        for (int u = 0; u < 8; ++u) {
            ob[(size_t)(cb + u) * HW] =
                w00 * v00[u] + w01 * v01[u] + w10 * v10[u] + w11 * v11[u];
        }
    }
}

extern "C" void kernel_launch(void* const* d_in, const int* in_sizes, int n_in,
                              void* d_out, int out_size, void* d_ws, size_t ws_size,
                              hipStream_t stream) {
    const float* img  = (const float*)d_in[0];
    const float* flow = (const float*)d_in[1];
    float* out = (float*)d_out;

    if (ws_size >= WS_NEEDED && d_ws != nullptr) {
        float* tmp = (float*)d_ws;
        transpose_kernel<<<dim3(NBLOCKS_V2), dim3(BLK), 0, stream>>>(img, tmp);
        gather_kernel<<<dim3(NBLOCKS_V2), dim3(BLK), 0, stream>>>(tmp, flow, out);
    } else {
        warp_kernel<<<dim3(NBLOCKS_V1), dim3(BLK), 0, stream>>>(img, flow, out);
    }
}

// Round 3
// 507.571 us; speedup vs baseline: 1.2649x; 1.0046x over previous
//
#include <hip/hip_runtime.h>

// Bilinear flow warp: input1 [B,C,H,W] fp32, input2 [B,2,H,W] flow (dx,dy).
// out[b,c,i,j] = bilinear sample of input1[b,c] at (i+fy, j+fx), OOB -> 0.
//
// v4: (a) transpose retiled to 128px x 64ch: 512B read granules, fully
// contiguous 32KB writes per block (v3 scattered 256B granules both sides ->
// 4.1TB/s). (b) gather main loop decoupled from SGPR chains: ds_bpermute
// broadcasts corner offsets/weights as VGPRs (one shared SGPR base), and
// loads are issued in batches of 32 (8 px x 4 corners) before any consume
// -> 4x more loads in flight, hides L2/HBM gather latency.
constexpr int B = 8, C = 64, H = 256, W = 448;
constexpr int HW = H * W;          // 114688
constexpr int NPIX = B * HW;       // 917504
constexpr int BLK = 256;
constexpr int XCDS = 8;

// ---- fallback (v1) config ----
constexpr int NBLOCKS_V1 = NPIX / BLK;              // 3584
constexpr int BLOCKS_PER_XCD_V1 = NBLOCKS_V1 / XCDS;

// ---- gather config ----
constexpr int TILE = 64;                            // pixels per block / channels
constexpr int TILES_PER_ROW = W / TILE;             // 7
constexpr int TILES_PER_IMG = HW / TILE;            // 1792
constexpr int NBLOCKS_G = B * TILES_PER_IMG;        // 14336
constexpr int BLOCKS_PER_XCD_G = NBLOCKS_G / XCDS;  // 1792 == one image per XCD
constexpr size_t WS_NEEDED = (size_t)B * HW * C * sizeof(float); // 224 MB

// ---- transpose config ----
constexpr int TP_PX = 128;                          // pixels per transpose tile
constexpr int NBLOCKS_T = NPIX / TP_PX;             // 7168

// ---------------------------------------------------------------------------
// Kernel A: [B,C,HW] -> [B,HW,C] transpose, 128px x 64ch tile.
// Reads: 512B contiguous per (channel, wave-chunk). Writes: the whole
// 128*64*4 = 32KB destination block is contiguous -> pure streaming.
// LDS [64][129]: every access pattern below is <=2-way (free).
// ---------------------------------------------------------------------------
__global__ __launch_bounds__(256) void transpose_kernel(
    const float* __restrict__ img,   // [B,C,HW]
    float* __restrict__ tmp)         // [B,HW,C]
{
    __shared__ float lds[64][129];   // 33KB -> 4 blocks/CU

    int blk = blockIdx.x;
    int b   = blk / (HW / TP_PX);
    int t   = blk - b * (HW / TP_PX);
    int hw0 = t * TP_PX;

    int tid = threadIdx.x;
    int pc  = tid & 15;              // px chunk (x4)
    int cg  = tid >> 4;              // 0..15

    // load: 8 iters; wave reads 4 channels x 256B contiguous segments
    const float* src = img + (size_t)b * C * HW + hw0 + 4 * pc;
    #pragma unroll
    for (int k = 0; k < 8; ++k) {
        int c   = cg + 16 * (k & 3);
        int px0 = 64 * (k >> 2);
        float4 v = *(const float4*)(src + (size_t)c * HW + px0);
        // bank = (c + px0 + 4pc + u) mod 32; c+4pc spans 64 distinct -> 2-way
        lds[c][px0 + 4 * pc + 0] = v.x;
        lds[c][px0 + 4 * pc + 1] = v.y;
        lds[c][px0 + 4 * pc + 2] = v.z;
        lds[c][px0 + 4 * pc + 3] = v.w;
    }
    __syncthreads();

    // store: linear float4 over the contiguous 32KB block
    // l = k*1024 + 4*tid  ->  px = l>>6, c = l&63
    int lt = tid & 15;
    int tg = tid >> 4;
    float* dst = tmp + ((size_t)b * HW + hw0) * C;
    #pragma unroll
    for (int k = 0; k < 8; ++k) {
        int px = 16 * k + tg;
        float4 v;
        // bank = (4lt + u + 16k + tg) mod 32; 4lt+tg spans 64 distinct -> 2-way
        v.x = lds[4 * lt + 0][px];
        v.y = lds[4 * lt + 1][px];
        v.z = lds[4 * lt + 2][px];
        v.w = lds[4 * lt + 3][px];
        *(float4*)(dst + k * 1024 + 4 * tid) = v;
    }
}

// ---------------------------------------------------------------------------
// Kernel B: gather from channels-last tmp. One block = 64 consecutive px of
// one row; each wave owns 16 px, lane = channel during gather.
// Metadata computed lane-parallel (pixel = wv*16 + (lane&15)); corner byte
// offsets + weights broadcast per-pixel via ds_bpermute (VGPR-uniform, no
// SGPR pressure). Loads issued in batches of 32 before any combine.
// ---------------------------------------------------------------------------
__global__ __launch_bounds__(256) void gather_kernel(
    const float* __restrict__ tmp,   // [B,HW,C]
    const float* __restrict__ flow,  // [B,2,H,W]
    float* __restrict__ out)         // [B,C,H,W]
{
    __shared__ float sm[64][65];     // [channel][pixel]

    // XCD swizzle: image b -> XCD b (gather band stays in one 4MB L2)
    int bid = blockIdx.x;
    int swz = (bid % XCDS) * BLOCKS_PER_XCD_G + (bid / XCDS);

    int b  = swz / TILES_PER_IMG;
    int t  = swz - b * TILES_PER_IMG;
    int i  = t / TILES_PER_ROW;
    int j0 = (t - i * TILES_PER_ROW) * TILE;

    int lane  = threadIdx.x & 63;
    int wv    = threadIdx.x >> 6;    // 0..3
    int lane4 = lane << 2;

    // ---- metadata for pixel p = wv*16 + (lane&15), lane-parallel
    int pl = lane & 15;
    int p1 = wv * 16 + pl;
    int j  = j0 + p1;
    int ij = i * W + j;

    const float* fb = flow + (size_t)b * 2 * HW;
    float fx = fb[ij];               // 16 consecutive addrs, coalesced
    float fy = fb[HW + ij];

    float x = (float)j + fx;
    float y = (float)i + fy;

    float x0f = floorf(x), y0f = floorf(y);
    int   x0  = (int)x0f,  y0  = (int)y0f;
    float wx1 = x - x0f,   wy1 = y - y0f;
    float wx0 = 1.0f - wx1, wy0 = 1.0f - wy1;

    // per-corner validity (matches reference: valid iff 0<=coord<=dim-1)
    bool vx0 = (x0 >= 0)  & (x0 <= W - 1);
    bool vx1 = (x0 >= -1) & (x0 <= W - 2);
    bool vy0 = (y0 >= 0)  & (y0 <= H - 1);
    bool vy1 = (y0 >= -1) & (y0 <= H - 2);

    float w00r = (vy0 & vx0) ? wy0 * wx0 : 0.0f;
    float w01r = (vy0 & vx1) ? wy0 * wx1 : 0.0f;
    float w10r = (vy1 & vx0) ? wy1 * wx0 : 0.0f;
    float w11r = (vy1 & vx1) ? wy1 * wx1 : 0.0f;

    int xi0 = min(max(x0, 0),     W - 1);
    int xi1 = min(max(x0 + 1, 0), W - 1);
    int yi0 = min(max(y0, 0),     H - 1);
    int yi1 = min(max(y0 + 1, 0), H - 1);

    // byte offsets into this image's channels-last block: (y*W+x)*C*4
    int o00r = (yi0 * W + xi0) << 8;
    int o01r = (yi0 * W + xi1) << 8;
    int o10r = (yi1 * W + xi0) << 8;
    int o11r = (yi1 * W + xi1) << 8;

    const char* tb = (const char*)(tmp + (size_t)b * HW * C);

    // ---- main loop: two batches of 8 pixels; 32 loads in flight per batch
    #pragma unroll
    for (int h = 0; h < 2; ++h) {
        float vv[8][4];
        // issue all 32 gathers back-to-back (bpermute-broadcast offsets,
        // shared SGPR base, vaddr = offset + lane*4)
        #pragma unroll
        for (int pp = 0; pp < 8; ++pp) {
            int idx = (h * 8 + pp) << 2;   // bpermute byte index -> lane sp
            int o0 = __builtin_amdgcn_ds_bpermute(idx, o00r);
            int o1 = __builtin_amdgcn_ds_bpermute(idx, o01r);
            int o2 = __builtin_amdgcn_ds_bpermute(idx, o10r);
            int o3 = __builtin_amdgcn_ds_bpermute(idx, o11r);
            vv[pp][0] = *(const float*)(tb + (unsigned)(o0 + lane4));
            vv[pp][1] = *(const float*)(tb + (unsigned)(o1 + lane4));
            vv[pp][2] = *(const float*)(tb + (unsigned)(o2 + lane4));
            vv[pp][3] = *(const float*)(tb + (unsigned)(o3 + lane4));
        }
        // combine: bpermute-broadcast weights, 4 fma per pixel
        #pragma unroll
        for (int pp = 0; pp < 8; ++pp) {
            int idx = (h * 8 + pp) << 2;
            float w0 = __int_as_float(__builtin_amdgcn_ds_bpermute(idx, __float_as_int(w00r)));
            float w1 = __int_as_float(__builtin_amdgcn_ds_bpermute(idx, __float_as_int(w01r)));
            float w2 = __int_as_float(__builtin_amdgcn_ds_bpermute(idx, __float_as_int(w10r)));
            float w3 = __int_as_float(__builtin_amdgcn_ds_bpermute(idx, __float_as_int(w11r)));
            float acc = w0 * vv[pp][0] + w1 * vv[pp][1]
                      + w2 * vv[pp][2] + w3 * vv[pp][3];
            // bank = (lane + const) mod 32 -> 2-way, free
            sm[lane][wv * 16 + h * 8 + pp] = acc;
        }
    }
    __syncthreads();

    // ---- write-out: float4 along px, coalesced 256B per channel row
    int pg = threadIdx.x & 15;       // px chunk
    int cg = threadIdx.x >> 4;       // 0..15
    float* ob = out + (size_t)b * C * HW + (size_t)i * W + j0 + 4 * pg;
    #pragma unroll
    for (int k = 0; k < 4; ++k) {
        int c = cg + 16 * k;
        float4 v;
        // bank = (c + 4pg + u) mod 32 -> 2-way, free
        v.x = sm[c][4 * pg + 0];
        v.y = sm[c][4 * pg + 1];
        v.z = sm[c][4 * pg + 2];
        v.w = sm[c][4 * pg + 3];
        *(float4*)(ob + (size_t)c * HW) = v;
    }
}

// ---------------------------------------------------------------------------
// Fallback (v1, proven 377us/dispatch): used only if workspace is too small.
// ---------------------------------------------------------------------------
__global__ __launch_bounds__(256) void warp_kernel(
    const float* __restrict__ img,
    const float* __restrict__ flow,
    float* __restrict__ out)
{
    int bid = blockIdx.x;
    int swz = (bid % XCDS) * BLOCKS_PER_XCD_V1 + (bid / XCDS);
    int pix = swz * BLK + threadIdx.x;

    int b  = pix / HW;
    int ij = pix - b * HW;
    int i  = ij / W;
    int j  = ij - i * W;

    float fx = flow[(size_t)(b * 2 + 0) * HW + ij];
    float fy = flow[(size_t)(b * 2 + 1) * HW + ij];

    float x = (float)j + fx;
    float y = (float)i + fy;

    float x0f = floorf(x), y0f = floorf(y);
    int   x0  = (int)x0f,  y0  = (int)y0f;
    float wx1 = x - x0f,   wy1 = y - y0f;
    float wx0 = 1.0f - wx1, wy0 = 1.0f - wy1;

    bool vx0 = (x0 >= 0)  & (x0 <= W - 1);
    bool vx1 = (x0 >= -1) & (x0 <= W - 2);
    bool vy0 = (y0 >= 0)  & (y0 <= H - 1);
    bool vy1 = (y0 >= -1) & (y0 <= H - 2);

    float w00 = (vy0 & vx0) ? wy0 * wx0 : 0.0f;
    float w01 = (vy0 & vx1) ? wy0 * wx1 : 0.0f;
    float w10 = (vy1 & vx0) ? wy1 * wx0 : 0.0f;
    float w11 = (vy1 & vx1) ? wy1 * wx1 : 0.0f;

    int xi0 = min(max(x0, 0),     W - 1);
    int xi1 = min(max(x0 + 1, 0), W - 1);
    int yi0 = min(max(y0, 0),     H - 1);
    int yi1 = min(max(y0 + 1, 0), H - 1);

    int o00 = yi0 * W + xi0;
    int o01 = yi0 * W + xi1;
    int o10 = yi1 * W + xi0;
    int o11 = yi1 * W + xi1;

    const float* ib = img + (size_t)b * C * HW;
    float*       ob = out + (size_t)b * C * HW + ij;

    #pragma unroll
    for (int cb = 0; cb < C; cb += 8) {
        float v00[8], v01[8], v10[8], v11[8];
        #pragma unroll
        for (int u = 0; u < 8; ++u) {
            const float* q = ib + (size_t)(cb + u) * HW;
            v00[u] = q[o00];
            v01[u] = q[o01];
            v10[u] = q[o10];
            v11[u] = q[o11];
        }
        #pragma unroll
        for (int u = 0; u < 8; ++u) {
            ob[(size_t)(cb + u) * HW] =
                w00 * v00[u] + w01 * v01[u] + w10 * v10[u] + w11 * v11[u];
        }
    }
}

extern "C" void kernel_launch(void* const* d_in, const int* in_sizes, int n_in,
                              void* d_out, int out_size, void* d_ws, size_t ws_size,
                              hipStream_t stream) {
    const float* img  = (const float*)d_in[0];
    const float* flow = (const float*)d_in[1];
    float* out = (float*)d_out;

    if (ws_size >= WS_NEEDED && d_ws != nullptr) {
        float* tmp = (float*)d_ws;
        transpose_kernel<<<dim3(NBLOCKS_T), dim3(BLK), 0, stream>>>(img, tmp);
        gather_kernel<<<dim3(NBLOCKS_G), dim3(BLK), 0, stream>>>(tmp, flow, out);
    } else {
        warp_kernel<<<dim3(NBLOCKS_V1), dim3(BLK), 0, stream>>>(img, flow, out);
    }
}